// Round 5
// baseline (1154.213 us; speedup 1.0000x reference)
//
#include <hip/hip_runtime.h>

// Kuramoto phase dynamics + coherence softmax. B*S=1024 rows, V=50257, 10 steps.
// One 1024-thread block per row. Phase state fully on-chip:
//   - p[11] + wr[11] in registers (22 regs of state; backend pins 64 VGPRs,
//     this fits with scheduling temps -> no scratch)
//   - 39 elems/thread in LDS (159.7 KiB, [k][tid] thread-private columns,
//     conflict-free, no barriers needed for private access)
// NO __sincosf: its ocml lowering writes the cos result through a stack
// pointer that is never promoted -> 1 scratch store + 1 scratch reload per
// call = the 2.3 GB/dispatch HBM excess seen in rounds 3-4. __sinf/__cosf
// stay fully in registers.
// Single fused pass per step: update with previous-step row sums, accumulate
// first-order-corrected post-update sin/cos (sin(p+d) ~= s + c*d). Resulting
// output error ~1e-8 vs 6.6e-7 threshold.

#define V_DIM    50257
#define NROWS    1024
#define NTHREADS 1024
#define NREG     11
#define NLDS     39
#define N_STEPS  10

__device__ __forceinline__ void block_reduce2(float& a, float& b, float* red) {
    #pragma unroll
    for (int off = 32; off > 0; off >>= 1) {
        a += __shfl_xor(a, off, 64);
        b += __shfl_xor(b, off, 64);
    }
    const int wid = threadIdx.x >> 6;   // 16 waves
    if ((threadIdx.x & 63) == 0) { red[wid] = a; red[16 + wid] = b; }
    __syncthreads();
    float ta = 0.f, tb = 0.f;
    #pragma unroll
    for (int i = 0; i < NTHREADS / 64; ++i) { ta += red[i]; tb += red[16 + i]; }
    __syncthreads();
    a = ta; b = tb;
}

__global__ __launch_bounds__(NTHREADS)
void kuramoto_kernel(const float* __restrict__ logits,
                     const float* __restrict__ omega,
                     const float* __restrict__ noise,
                     float* __restrict__ out) {
    __shared__ float pl[NLDS][NTHREADS];   // 159,744 B, thread-private columns
    __shared__ float red[32];

    const int tid = threadIdx.x;
    const size_t base = (size_t)blockIdx.x * V_DIM;
    const float* __restrict__ lg = logits + base;
    const float* __restrict__ nz = noise + base;
    float* __restrict__ op = out + base;

    const float dtc = 0.1f * (0.1f / (float)V_DIM);   // DT * coupling

    // ---- init: phases = noise + 0.1*logits; initial row sums of sin/cos ----
    float p[NREG], wr[NREG];
    float ss = 0.f, cc = 0.f;
    #pragma unroll
    for (int k = 0; k < NREG; ++k) {
        const int idx = tid + k * NTHREADS;           // max 11263 < V_DIM
        const float ph = nz[idx] + 0.1f * lg[idx];
        p[k]  = ph;
        wr[k] = 0.1f * omega[idx];
        ss += __sinf(ph);
        cc += __cosf(ph);
    }
    #pragma unroll
    for (int k = 0; k < NLDS; ++k) {
        const int idx = tid + (NREG + k) * NTHREADS;
        if (idx < V_DIM) {
            const float ph = nz[idx] + 0.1f * lg[idx];
            pl[k][tid] = ph;
            ss += __sinf(ph);
            cc += __cosf(ph);
        }
    }
    block_reduce2(ss, cc, red);
    float S = ss, C = cc;   // row-wide sum(sin), sum(cos) of current phases

    // ---- 10 fused steps ----
    for (int st = 0; st < N_STEPS; ++st) {
        float nss = 0.f, ncc = 0.f;
        #pragma unroll
        for (int k = 0; k < NREG; ++k) {
            const float s = __sinf(p[k]);
            const float c = __cosf(p[k]);
            const float d = wr[k] + dtc * (s * C - c * S);
            p[k] += d;
            nss += s + c * d;        // ~= sin(p+d)
            ncc += c - s * d;        // ~= cos(p+d)
        }
        #pragma unroll
        for (int k = 0; k < NLDS; ++k) {
            const int idx = tid + (NREG + k) * NTHREADS;
            if (idx < V_DIM) {
                const float ph = pl[k][tid];
                const float s = __sinf(ph);
                const float c = __cosf(ph);
                const float d = 0.1f * omega[idx] + dtc * (s * C - c * S);
                pl[k][tid] = ph + d;
                nss += s + c * d;
                ncc += c - s * d;
            }
        }
        block_reduce2(nss, ncc, red);
        S = nss; C = ncc;
    }

    // ---- mean(phases) ----
    float psum = 0.f, d0 = 0.f;
    #pragma unroll
    for (int k = 0; k < NREG; ++k) psum += p[k];
    #pragma unroll
    for (int k = 0; k < NLDS; ++k) {
        const int idx = tid + (NREG + k) * NTHREADS;
        if (idx < V_DIM) psum += pl[k][tid];
    }
    block_reduce2(psum, d0, red);
    const float mean = psum / (float)V_DIM;

    // ---- e = exp(cos(p - mean)); store e in place; reduce sum ----
    float esum = 0.f, d1 = 0.f;
    #pragma unroll
    for (int k = 0; k < NREG; ++k) {
        const float e = __expf(__cosf(p[k] - mean));
        p[k] = e;
        esum += e;
    }
    #pragma unroll
    for (int k = 0; k < NLDS; ++k) {
        const int idx = tid + (NREG + k) * NTHREADS;
        if (idx < V_DIM) {
            const float e = __expf(__cosf(pl[k][tid] - mean));
            pl[k][tid] = e;
            esum += e;
        }
    }
    block_reduce2(esum, d1, red);
    const float inv = 1.f / esum;

    #pragma unroll
    for (int k = 0; k < NREG; ++k) {
        op[tid + k * NTHREADS] = p[k] * inv;
    }
    #pragma unroll
    for (int k = 0; k < NLDS; ++k) {
        const int idx = tid + (NREG + k) * NTHREADS;
        if (idx < V_DIM) op[idx] = pl[k][tid] * inv;
    }
}

extern "C" void kernel_launch(void* const* d_in, const int* in_sizes, int n_in,
                              void* d_out, int out_size, void* d_ws, size_t ws_size,
                              hipStream_t stream) {
    const float* logits = (const float*)d_in[0];
    const float* omega  = (const float*)d_in[1];  // natural_frequencies [V]
    const float* noise  = (const float*)d_in[2];
    float* out = (float*)d_out;
    (void)d_ws; (void)ws_size; (void)in_sizes; (void)n_in; (void)out_size;

    kuramoto_kernel<<<NROWS, NTHREADS, 0, stream>>>(logits, omega, noise, out);
}

// Round 6
// 568.877 us; speedup vs baseline: 2.0289x; 2.0289x over previous
//
#include <hip/hip_runtime.h>

// Kuramoto phase dynamics + coherence softmax. B*S=1024 rows, V=50257, 10 steps.
// One 768-thread block per row (12 waves = 3/SIMD at 1 block/CU, LDS-capped).
// Phase state fully on-chip:
//   - p[14] + wr[14] in registers (28 regs of state)
//   - 52 elems/thread in LDS (pl[52][768] = 159.7 KiB, [k][tid] thread-private
//     columns, conflict-free, no barriers needed for private access)
// r3-r5 evidence: the fused per-element body at a 64-VGPR allocation spills
// ~1 value per element per step (~2.3 GB of scratch HBM writes, invariant to
// NREG/NLDS split). Two fixes here:
//   1) __launch_bounds__(768, 3): 3 waves/EU min -> VGPR cap ~170 (occupancy
//      is LDS-capped at 12 waves/CU regardless, so nothing is lost)
//   2) #pragma unroll 8 on the LDS-slice loops bounds the scheduler's
//      overlapped live ranges (~8 elems * 4 temps) to fit even a 64-reg alloc.
// Single fused pass per step: update with previous-step row sums, accumulate
// first-order-corrected post-update sin/cos (sin(p+d) ~= s + c*d). Phase error
// ~3e-6 -> output error ~1e-10 vs 6.6e-7 threshold (absmax unchanged r3-r5).

#define V_DIM    50257
#define NROWS    1024
#define NTHREADS 768
#define NWAVES   (NTHREADS / 64)
#define NREG     14
#define NLDS     52
#define N_STEPS  10

__device__ __forceinline__ void block_reduce2(float& a, float& b, float* red) {
    #pragma unroll
    for (int off = 32; off > 0; off >>= 1) {
        a += __shfl_xor(a, off, 64);
        b += __shfl_xor(b, off, 64);
    }
    const int wid = threadIdx.x >> 6;   // 12 waves
    if ((threadIdx.x & 63) == 0) { red[wid] = a; red[16 + wid] = b; }
    __syncthreads();
    float ta = 0.f, tb = 0.f;
    #pragma unroll
    for (int i = 0; i < NWAVES; ++i) { ta += red[i]; tb += red[16 + i]; }
    __syncthreads();
    a = ta; b = tb;
}

__global__ __launch_bounds__(NTHREADS, 3)
void kuramoto_kernel(const float* __restrict__ logits,
                     const float* __restrict__ omega,
                     const float* __restrict__ noise,
                     float* __restrict__ out) {
    __shared__ float pl[NLDS][NTHREADS];   // 159,744 B, thread-private columns
    __shared__ float red[32];

    const int tid = threadIdx.x;
    const size_t base = (size_t)blockIdx.x * V_DIM;
    const float* __restrict__ lg = logits + base;
    const float* __restrict__ nz = noise + base;
    float* __restrict__ op = out + base;

    const float dtc = 0.1f * (0.1f / (float)V_DIM);   // DT * coupling

    // ---- init: phases = noise + 0.1*logits; initial row sums of sin/cos ----
    float p[NREG], wr[NREG];
    float ss = 0.f, cc = 0.f;
    #pragma unroll
    for (int k = 0; k < NREG; ++k) {
        const int idx = tid + k * NTHREADS;           // max 10751 < V_DIM
        const float ph = nz[idx] + 0.1f * lg[idx];
        p[k]  = ph;
        wr[k] = 0.1f * omega[idx];
        ss += __sinf(ph);
        cc += __cosf(ph);
    }
    #pragma unroll 8
    for (int k = 0; k < NLDS; ++k) {
        const int idx = tid + (NREG + k) * NTHREADS;
        if (idx < V_DIM) {
            const float ph = nz[idx] + 0.1f * lg[idx];
            pl[k][tid] = ph;
            ss += __sinf(ph);
            cc += __cosf(ph);
        }
    }
    block_reduce2(ss, cc, red);
    float S = ss, C = cc;   // row-wide sum(sin), sum(cos) of current phases

    // ---- 10 fused steps ----
    for (int st = 0; st < N_STEPS; ++st) {
        float nss = 0.f, ncc = 0.f;
        #pragma unroll
        for (int k = 0; k < NREG; ++k) {
            const float s = __sinf(p[k]);
            const float c = __cosf(p[k]);
            const float d = wr[k] + dtc * (s * C - c * S);
            p[k] += d;
            nss += s + c * d;        // ~= sin(p+d)
            ncc += c - s * d;        // ~= cos(p+d)
        }
        #pragma unroll 8
        for (int k = 0; k < NLDS; ++k) {
            const int idx = tid + (NREG + k) * NTHREADS;
            if (idx < V_DIM) {
                const float ph = pl[k][tid];
                const float s = __sinf(ph);
                const float c = __cosf(ph);
                const float d = 0.1f * omega[idx] + dtc * (s * C - c * S);
                pl[k][tid] = ph + d;
                nss += s + c * d;
                ncc += c - s * d;
            }
        }
        block_reduce2(nss, ncc, red);
        S = nss; C = ncc;
    }

    // ---- mean(phases) ----
    float psum = 0.f, d0 = 0.f;
    #pragma unroll
    for (int k = 0; k < NREG; ++k) psum += p[k];
    #pragma unroll 8
    for (int k = 0; k < NLDS; ++k) {
        const int idx = tid + (NREG + k) * NTHREADS;
        if (idx < V_DIM) psum += pl[k][tid];
    }
    block_reduce2(psum, d0, red);
    const float mean = psum / (float)V_DIM;

    // ---- e = exp(cos(p - mean)); store e in place; reduce sum ----
    float esum = 0.f, d1 = 0.f;
    #pragma unroll
    for (int k = 0; k < NREG; ++k) {
        const float e = __expf(__cosf(p[k] - mean));
        p[k] = e;
        esum += e;
    }
    #pragma unroll 8
    for (int k = 0; k < NLDS; ++k) {
        const int idx = tid + (NREG + k) * NTHREADS;
        if (idx < V_DIM) {
            const float e = __expf(__cosf(pl[k][tid] - mean));
            pl[k][tid] = e;
            esum += e;
        }
    }
    block_reduce2(esum, d1, red);
    const float inv = 1.f / esum;

    #pragma unroll
    for (int k = 0; k < NREG; ++k) {
        op[tid + k * NTHREADS] = p[k] * inv;
    }
    #pragma unroll 8
    for (int k = 0; k < NLDS; ++k) {
        const int idx = tid + (NREG + k) * NTHREADS;
        if (idx < V_DIM) op[idx] = pl[k][tid] * inv;
    }
}

extern "C" void kernel_launch(void* const* d_in, const int* in_sizes, int n_in,
                              void* d_out, int out_size, void* d_ws, size_t ws_size,
                              hipStream_t stream) {
    const float* logits = (const float*)d_in[0];
    const float* omega  = (const float*)d_in[1];  // natural_frequencies [V]
    const float* noise  = (const float*)d_in[2];
    float* out = (float*)d_out;
    (void)d_ws; (void)ws_size; (void)in_sizes; (void)n_in; (void)out_size;

    kuramoto_kernel<<<NROWS, NTHREADS, 0, stream>>>(logits, omega, noise, out);
}

// Round 7
// 349.885 us; speedup vs baseline: 3.2988x; 1.6259x over previous
//
#include <hip/hip_runtime.h>

// Kuramoto phase dynamics + coherence softmax. B*S=1024 rows, V=50257, 10 steps.
// One 768-thread block per row (12 waves; 1 block/CU, LDS-capped). State:
//   - p[20] + wr[20] in registers (pair-mapped, float2 global I/O)
//   - 44 elems/thread in LDS as float2 pairs (pl2[22][768]) + 2 scalar tail
//     planes; [j][tid] layout -> thread-private, conflict-free b64 access
// Per step (single fused pass): s,c = sin/cos(p) via shared range reduction
// (v_sin/v_cos on p/2pi); d = 0.1*omega + dtc*(s*C - c*S); p += d; accumulate
// plain sums (S,C lag one step: error ~4e-6 rad/step -> ~1e-9 on output vs
// 6.6e-7 threshold). One barrier per step via double-buffered red[2][32].
// Step 9 peeled: accumulates sum(p) instead of sums (kills the mean pass).
// unroll 4 on pair loops bounds live ranges (r5 lesson: full unroll spills).

#define V_DIM    50257
#define NROWS    1024
#define NT       768
#define NREG     20
#define NPAIR    22
#define REG_E    (NREG * NT)              // 15360
#define PAIR_B   REG_E                    // 15360
#define TAIL0_B  (PAIR_B + NPAIR * 2 * NT) // 49152
#define TAIL1_B  (TAIL0_B + NT)           // 49920
#define TAIL1_N  (V_DIM - TAIL1_B)        // 337
#define INV2PI   0.15915494309189535f

__device__ __forceinline__ float fsin(float r) { return __builtin_amdgcn_sinf(r); }
__device__ __forceinline__ float fcos(float r) { return __builtin_amdgcn_cosf(r); }

// One-barrier block reduction of (a,b) across 12 waves; red points at a
// 32-float buffer unique to this call's parity (alternate between calls).
__device__ __forceinline__ void block_reduce2(float& a, float& b, float* red) {
    #pragma unroll
    for (int off = 32; off > 0; off >>= 1) {
        a += __shfl_xor(a, off, 64);
        b += __shfl_xor(b, off, 64);
    }
    const int wid = threadIdx.x >> 6;
    if ((threadIdx.x & 63) == 0) { red[wid] = a; red[16 + wid] = b; }
    __syncthreads();
    float ta = 0.f, tb = 0.f;
    #pragma unroll
    for (int i = 0; i < NT / 64; ++i) { ta += red[i]; tb += red[16 + i]; }
    a = ta; b = tb;
}

__global__ __launch_bounds__(NT, 3)
void kuramoto_kernel(const float* __restrict__ logits,
                     const float* __restrict__ omega,
                     const float* __restrict__ noise,
                     float* __restrict__ out) {
    __shared__ float2 pl2[NPAIR][NT];   // 135168 B
    __shared__ float  pt0[NT];          // tail plane 0 (full)
    __shared__ float  pt1[NT];          // tail plane 1 (first 337 tids)
    __shared__ float  red[2][32];

    const int tid = threadIdx.x;
    const size_t base = (size_t)blockIdx.x * V_DIM;
    const float* __restrict__ lg = logits + base;
    const float* __restrict__ nz = noise + base;
    float* __restrict__ op = out + base;

    const float dtc = 0.1f * (0.1f / (float)V_DIM);   // DT * coupling
    int rp = 0;                                        // reduce-buffer parity

    // ---- init: phases = noise + 0.1*logits; sums of sin/cos of p0 ----
    float p[NREG], wr[NREG];
    float ss = 0.f, cc = 0.f;
    #pragma unroll
    for (int kk = 0; kk < NREG / 2; ++kk) {
        const int e = kk * (2 * NT) + 2 * tid;        // pair (e, e+1), coalesced
        const float2 l2 = *(const float2*)(lg + e);
        const float2 n2 = *(const float2*)(nz + e);
        const float2 o2 = *(const float2*)(omega + e);
        const float phx = n2.x + 0.1f * l2.x;
        const float phy = n2.y + 0.1f * l2.y;
        p[2 * kk]     = phx; wr[2 * kk]     = 0.1f * o2.x;
        p[2 * kk + 1] = phy; wr[2 * kk + 1] = 0.1f * o2.y;
        ss += fsin(phx * INV2PI) + fsin(phy * INV2PI);
        cc += fcos(phx * INV2PI) + fcos(phy * INV2PI);
    }
    #pragma unroll 4
    for (int j = 0; j < NPAIR; ++j) {
        const int e = PAIR_B + j * (2 * NT) + 2 * tid;
        const float2 l2 = *(const float2*)(lg + e);
        const float2 n2 = *(const float2*)(nz + e);
        const float phx = n2.x + 0.1f * l2.x;
        const float phy = n2.y + 0.1f * l2.y;
        pl2[j][tid] = make_float2(phx, phy);
        ss += fsin(phx * INV2PI) + fsin(phy * INV2PI);
        cc += fcos(phx * INV2PI) + fcos(phy * INV2PI);
    }
    {   // tail planes
        const int e0 = TAIL0_B + tid;
        const float ph0 = nz[e0] + 0.1f * lg[e0];
        pt0[tid] = ph0;
        ss += fsin(ph0 * INV2PI); cc += fcos(ph0 * INV2PI);
        if (tid < TAIL1_N) {
            const int e1 = TAIL1_B + tid;
            const float ph1 = nz[e1] + 0.1f * lg[e1];
            pt1[tid] = ph1;
            ss += fsin(ph1 * INV2PI); cc += fcos(ph1 * INV2PI);
        }
    }
    block_reduce2(ss, cc, red[rp]); rp ^= 1;
    float S = ss, C = cc;

    // ---- steps 0..8: update + accumulate (lagged) sums ----
    for (int st = 0; st < 9; ++st) {
        const float dC = dtc * C, dS = dtc * S;
        float nss = 0.f, ncc = 0.f;
        #pragma unroll
        for (int k = 0; k < NREG; ++k) {
            const float r = p[k] * INV2PI;
            const float s = fsin(r), c = fcos(r);
            p[k] += wr[k] + (s * dC - c * dS);
            nss += s; ncc += c;
        }
        #pragma unroll 4
        for (int j = 0; j < NPAIR; ++j) {
            float2 ph = pl2[j][tid];
            const int e = PAIR_B + j * (2 * NT) + 2 * tid;
            const float2 o2 = *(const float2*)(omega + e);
            const float rx = ph.x * INV2PI, ry = ph.y * INV2PI;
            const float sx = fsin(rx), cx = fcos(rx);
            const float sy = fsin(ry), cy = fcos(ry);
            ph.x += 0.1f * o2.x + (sx * dC - cx * dS);
            ph.y += 0.1f * o2.y + (sy * dC - cy * dS);
            pl2[j][tid] = ph;
            nss += sx + sy; ncc += cx + cy;
        }
        {
            float ph0 = pt0[tid];
            const float r0 = ph0 * INV2PI;
            const float s0 = fsin(r0), c0 = fcos(r0);
            pt0[tid] = ph0 + 0.1f * omega[TAIL0_B + tid] + (s0 * dC - c0 * dS);
            nss += s0; ncc += c0;
            if (tid < TAIL1_N) {
                float ph1 = pt1[tid];
                const float r1 = ph1 * INV2PI;
                const float s1 = fsin(r1), c1 = fcos(r1);
                pt1[tid] = ph1 + 0.1f * omega[TAIL1_B + tid] + (s1 * dC - c1 * dS);
                nss += s1; ncc += c1;
            }
        }
        block_reduce2(nss, ncc, red[rp]); rp ^= 1;
        S = nss; C = ncc;
    }

    // ---- step 9 (peeled): update + accumulate sum(p_final) ----
    float psum = 0.f, d0 = 0.f;
    {
        const float dC = dtc * C, dS = dtc * S;
        #pragma unroll
        for (int k = 0; k < NREG; ++k) {
            const float r = p[k] * INV2PI;
            const float s = fsin(r), c = fcos(r);
            p[k] += wr[k] + (s * dC - c * dS);
            psum += p[k];
        }
        #pragma unroll 4
        for (int j = 0; j < NPAIR; ++j) {
            float2 ph = pl2[j][tid];
            const int e = PAIR_B + j * (2 * NT) + 2 * tid;
            const float2 o2 = *(const float2*)(omega + e);
            const float rx = ph.x * INV2PI, ry = ph.y * INV2PI;
            ph.x += 0.1f * o2.x + (fsin(rx) * dC - fcos(rx) * dS);
            ph.y += 0.1f * o2.y + (fsin(ry) * dC - fcos(ry) * dS);
            pl2[j][tid] = ph;
            psum += ph.x + ph.y;
        }
        {
            float ph0 = pt0[tid];
            const float r0 = ph0 * INV2PI;
            ph0 += 0.1f * omega[TAIL0_B + tid] + (fsin(r0) * dC - fcos(r0) * dS);
            pt0[tid] = ph0;
            psum += ph0;
            if (tid < TAIL1_N) {
                float ph1 = pt1[tid];
                const float r1 = ph1 * INV2PI;
                ph1 += 0.1f * omega[TAIL1_B + tid] + (fsin(r1) * dC - fcos(r1) * dS);
                pt1[tid] = ph1;
                psum += ph1;
            }
        }
    }
    block_reduce2(psum, d0, red[rp]); rp ^= 1;
    const float mean = psum / (float)V_DIM;

    // ---- e = exp(cos(p - mean)) in place; reduce esum ----
    float esum = 0.f, d1 = 0.f;
    #pragma unroll
    for (int k = 0; k < NREG; ++k) {
        const float e = __expf(fcos((p[k] - mean) * INV2PI));
        p[k] = e;
        esum += e;
    }
    #pragma unroll 4
    for (int j = 0; j < NPAIR; ++j) {
        float2 ph = pl2[j][tid];
        const float ex = __expf(fcos((ph.x - mean) * INV2PI));
        const float ey = __expf(fcos((ph.y - mean) * INV2PI));
        pl2[j][tid] = make_float2(ex, ey);
        esum += ex + ey;
    }
    {
        const float e0 = __expf(fcos((pt0[tid] - mean) * INV2PI));
        pt0[tid] = e0;
        esum += e0;
        if (tid < TAIL1_N) {
            const float e1 = __expf(fcos((pt1[tid] - mean) * INV2PI));
            pt1[tid] = e1;
            esum += e1;
        }
    }
    block_reduce2(esum, d1, red[rp]); rp ^= 1;
    const float inv = 1.f / esum;

    // ---- stores (dwordx2 on paired regions) ----
    #pragma unroll
    for (int kk = 0; kk < NREG / 2; ++kk) {
        const int e = kk * (2 * NT) + 2 * tid;
        *(float2*)(op + e) = make_float2(p[2 * kk] * inv, p[2 * kk + 1] * inv);
    }
    #pragma unroll 4
    for (int j = 0; j < NPAIR; ++j) {
        const int e = PAIR_B + j * (2 * NT) + 2 * tid;
        const float2 ph = pl2[j][tid];
        *(float2*)(op + e) = make_float2(ph.x * inv, ph.y * inv);
    }
    op[TAIL0_B + tid] = pt0[tid] * inv;
    if (tid < TAIL1_N) op[TAIL1_B + tid] = pt1[tid] * inv;
}

extern "C" void kernel_launch(void* const* d_in, const int* in_sizes, int n_in,
                              void* d_out, int out_size, void* d_ws, size_t ws_size,
                              hipStream_t stream) {
    const float* logits = (const float*)d_in[0];
    const float* omega  = (const float*)d_in[1];  // natural_frequencies [V]
    const float* noise  = (const float*)d_in[2];
    float* out = (float*)d_out;
    (void)d_ws; (void)ws_size; (void)in_sizes; (void)n_in; (void)out_size;

    kuramoto_kernel<<<NROWS, NT, 0, stream>>>(logits, omega, noise, out);
}